// Round 8
// baseline (2460.028 us; speedup 1.0000x reference)
//
#include <hip/hip_runtime.h>
#include <hip/hip_bf16.h>
#include <stdint.h>

// GraphInterConnection P=16,B=4,C=256,N=256.
// R8 = R6's fused zero-workspace kernel with the epilogue fixed to store FP32.
// Root cause of R3-R7: reference output dtype is float32 => d_out is float*;
// I was packing bf16 shorts into it (five pipelines failed bit-identically).
// Math per (p,q,b):
//   corr[j,d]=sum_c tf_p[c,j]We[d,c]; A[j,i]=sum_d corr[j,d]tf_q[d,i]
//   S=softmax_i(A[j,:]); g_q[i]=sum_c Wg[c]tf_q[c,i]
//   mask[j]=sigmoid(sum_i S[j,i]g_q[i]);  W=mask*S
//   out[p,b,c,j]=(1/pn)*sum_q sum_i W[j,i]tf_q[c,i]
// Inputs fp32 (auto-detect retained as insurance).

#define NB 4
#define NC 256
#define NN 256
#define SLAB 65536

typedef __attribute__((ext_vector_type(4))) float f4;

static __device__ __forceinline__ float b2f(unsigned short u) {
  union { unsigned u; float f; } x; x.u = ((unsigned)u) << 16; return x.f;
}
static __device__ __forceinline__ unsigned short f2b(float f) {
  unsigned u = __float_as_uint(f);
  u += 0x7fffu + ((u >> 16) & 1u);
  return (unsigned short)(u >> 16);
}
static __device__ __forceinline__ int is_bf16(const void* p) {
  const unsigned short* s = (const unsigned short*)p;
  int sane = 0;
  for (int i = 0; i < 64; ++i) {
    float av = fabsf(b2f(s[i]));
    sane += ((av == 0.0f) || (av > 8e-13f && av < 256.0f)) ? 1 : 0;
  }
  return sane >= 56;   // true bf16: 64/64; fp32-as-shorts: ~45/64
}
static __device__ __forceinline__ float ld1(const void* p, size_t idx, int isb) {
  return isb ? b2f(((const unsigned short*)p)[idx]) : ((const float*)p)[idx];
}
static __device__ __forceinline__ f4 ld4(const void* p, size_t idx, int isb) {
  if (isb) {
    ushort4 v = *(const ushort4*)((const unsigned short*)p + idx);
    f4 r; r[0] = b2f(v.x); r[1] = b2f(v.y); r[2] = b2f(v.z); r[3] = b2f(v.w);
    return r;
  }
  return *(const f4*)((const float*)p + idx);
}
static __device__ __forceinline__ float read_pn(const void* p) {
  int iv = *(const int*)p;
  if (iv >= 1 && iv <= 65536) return (float)iv;
  float fv = *(const float*)p;
  if (fv >= 1.0f && fv <= 65536.0f) return fv;
  return 16.0f;
}

// grid 256 = pb(64) x jt(4); 256 threads.
// dyn LDS floats: corr[16384] | uni[16384] | glds[256]  = 132,096 B
__global__ __launch_bounds__(256, 1)
void k_fused(const void* __restrict__ temp, const void* __restrict__ wev,
             const void* __restrict__ wgv, const void* __restrict__ pnv,
             float* __restrict__ out)
{
  extern __shared__ __align__(16) float sm[];
  float* corr = sm;                 // corr[d*64 + j]
  float* uni  = sm + 16384;
  float* glds = sm + 32768;         // g[256]

  const int tid = threadIdx.x;
  const int bx  = blockIdx.x;
  const int pb  = bx >> 2;          // p*4 + b
  const int b   = pb & 3;
  const int j0  = (bx & 3) * 64;

  const int tb = is_bf16(temp);
  const int eb = is_bf16(wev);
  const int gb = is_bf16(wgv);
  const float inv = 1.0f / read_pn(pnv);

  // ---- phase 1a: tfp[c][j0..j0+64) -> uni ----
  {
    float* tfp = uni;
    for (int it = 0; it < 16; ++it) {
      int slot = it * 256 + tid;          // 4096 f4 slots
      int c = slot >> 4, u = slot & 15;
      f4 v = ld4(temp, (size_t)pb * SLAB + (size_t)c * NN + j0 + u * 4, tb);
      *(f4*)(tfp + c * 64 + u * 4) = v;
    }
  }
  __syncthreads();

  // ---- phase 1b: corr[d][j] = sum_c tfp[c][j] * We[d][c]; thread = d ----
  {
    float cr[64];
#pragma unroll
    for (int j = 0; j < 64; ++j) cr[j] = 0.f;
    const float* tfp = uni;
    for (int c4 = 0; c4 < 64; ++c4) {
      f4 w = ld4(wev, (size_t)tid * NC + c4 * 4, eb);
#pragma unroll
      for (int cc = 0; cc < 4; ++cc) {
        const float* trow = tfp + (c4 * 4 + cc) * 64;
#pragma unroll
        for (int j4 = 0; j4 < 16; ++j4) {
          f4 t = *(const f4*)(trow + j4 * 4);
          cr[j4 * 4 + 0] = fmaf(w[cc], t[0], cr[j4 * 4 + 0]);
          cr[j4 * 4 + 1] = fmaf(w[cc], t[1], cr[j4 * 4 + 1]);
          cr[j4 * 4 + 2] = fmaf(w[cc], t[2], cr[j4 * 4 + 2]);
          cr[j4 * 4 + 3] = fmaf(w[cc], t[3], cr[j4 * 4 + 3]);
        }
      }
    }
#pragma unroll
    for (int j4 = 0; j4 < 16; ++j4)
      *(f4*)(corr + tid * 64 + j4 * 4) = *(f4*)(cr + j4 * 4);
  }
  __syncthreads();   // corr visible; tfp reads done -> uni reusable

  float* stage = uni;                                   // [32][256] fp32
  unsigned short* W = (unsigned short*)(uni + 8192);    // [64][256] bf16

  const int jq = tid >> 4;     // M1: j = j0 + jq*4 + r
  const int iq = tid & 15;     // M1: i = iq*16 + k

  float outacc[64];
#pragma unroll
  for (int j = 0; j < 64; ++j) outacc[j] = 0.f;

  for (int q = 0; q < 16; ++q) {
    const size_t qs = (size_t)(q * NB + b) * SLAB;

    float a[64];
#pragma unroll
    for (int v = 0; v < 64; ++v) a[v] = 0.f;
    float gacc = 0.f;

    // ---- M1 over 8 chunks of 32 channel-rows ----
    for (int ch = 0; ch < 8; ++ch) {
      __syncthreads();                     // protect stage (and W) from prev readers
#pragma unroll
      for (int it = 0; it < 8; ++it) {
        int slot = it * 256 + tid;         // 2048 f4 slots
        int r = slot >> 6, u = slot & 63;
        f4 v = ld4(temp, qs + (size_t)(ch * 32 + r) * NN + u * 4, tb);
        *(f4*)(stage + r * 256 + u * 4) = v;
      }
      __syncthreads();
      // g partial (thread <-> i = tid)
#pragma unroll
      for (int cl = 0; cl < 32; ++cl) {
        float wg = ld1(wgv, ch * 32 + cl, gb);
        gacc = fmaf(wg, stage[cl * 256 + tid], gacc);
      }
      // A partial
      for (int dl = 0; dl < 32; ++dl) {
        f4 cv = *(const f4*)(corr + (ch * 32 + dl) * 64 + jq * 4);
        const float* srow = stage + dl * 256 + iq * 16;
        f4 t0 = *(const f4*)(srow + 0);
        f4 t1 = *(const f4*)(srow + 4);
        f4 t2 = *(const f4*)(srow + 8);
        f4 t3 = *(const f4*)(srow + 12);
#pragma unroll
        for (int r = 0; r < 4; ++r) {
          a[r * 16 + 0]  = fmaf(cv[r], t0[0], a[r * 16 + 0]);
          a[r * 16 + 1]  = fmaf(cv[r], t0[1], a[r * 16 + 1]);
          a[r * 16 + 2]  = fmaf(cv[r], t0[2], a[r * 16 + 2]);
          a[r * 16 + 3]  = fmaf(cv[r], t0[3], a[r * 16 + 3]);
          a[r * 16 + 4]  = fmaf(cv[r], t1[0], a[r * 16 + 4]);
          a[r * 16 + 5]  = fmaf(cv[r], t1[1], a[r * 16 + 5]);
          a[r * 16 + 6]  = fmaf(cv[r], t1[2], a[r * 16 + 6]);
          a[r * 16 + 7]  = fmaf(cv[r], t1[3], a[r * 16 + 7]);
          a[r * 16 + 8]  = fmaf(cv[r], t2[0], a[r * 16 + 8]);
          a[r * 16 + 9]  = fmaf(cv[r], t2[1], a[r * 16 + 9]);
          a[r * 16 + 10] = fmaf(cv[r], t2[2], a[r * 16 + 10]);
          a[r * 16 + 11] = fmaf(cv[r], t2[3], a[r * 16 + 11]);
          a[r * 16 + 12] = fmaf(cv[r], t3[0], a[r * 16 + 12]);
          a[r * 16 + 13] = fmaf(cv[r], t3[1], a[r * 16 + 13]);
          a[r * 16 + 14] = fmaf(cv[r], t3[2], a[r * 16 + 14]);
          a[r * 16 + 15] = fmaf(cv[r], t3[3], a[r * 16 + 15]);
        }
      }
    }
    glds[tid] = gacc;
    __syncthreads();

    // ---- softmax over i (16-lane groups share jq) + fused gate ----
    float gl[16];
#pragma unroll
    for (int k = 0; k < 16; ++k) gl[k] = glds[iq * 16 + k];
#pragma unroll
    for (int r = 0; r < 4; ++r) {
      float m = a[r * 16];
#pragma unroll
      for (int k = 1; k < 16; ++k) m = fmaxf(m, a[r * 16 + k]);
      m = fmaxf(m, __shfl_xor(m, 1)); m = fmaxf(m, __shfl_xor(m, 2));
      m = fmaxf(m, __shfl_xor(m, 4)); m = fmaxf(m, __shfl_xor(m, 8));
      float z = 0.f, s = 0.f;
#pragma unroll
      for (int k = 0; k < 16; ++k) {
        float e = __expf(a[r * 16 + k] - m);
        a[r * 16 + k] = e;
        z += e; s = fmaf(e, gl[k], s);
      }
      z += __shfl_xor(z, 1); z += __shfl_xor(z, 2);
      z += __shfl_xor(z, 4); z += __shfl_xor(z, 8);
      s += __shfl_xor(s, 1); s += __shfl_xor(s, 2);
      s += __shfl_xor(s, 4); s += __shfl_xor(s, 8);
      float rz = 1.0f / z;
      float mask = 1.0f / (1.0f + __expf(-s * rz));
      float sc = mask * rz;
      unsigned short* wr = W + (jq * 4 + r) * 256 + iq * 16;
#pragma unroll
      for (int k4 = 0; k4 < 4; ++k4) {
        ushort4 pk;
        pk.x = f2b(a[r * 16 + k4 * 4 + 0] * sc);
        pk.y = f2b(a[r * 16 + k4 * 4 + 1] * sc);
        pk.z = f2b(a[r * 16 + k4 * 4 + 2] * sc);
        pk.w = f2b(a[r * 16 + k4 * 4 + 3] * sc);
        *(ushort4*)(wr + k4 * 4) = pk;
      }
    }
    __syncthreads();

    // ---- M2: thread <-> c=tid; outacc[jl] += sum_i W[jl][i]*tq[c][i] ----
    for (int i4 = 0; i4 < 64; ++i4) {
      f4 tv = ld4(temp, qs + (size_t)tid * NN + i4 * 4, tb);
#pragma unroll
      for (int jl = 0; jl < 64; ++jl) {
        const unsigned short* wr = W + jl * 256 + i4 * 4;   // wave-uniform -> broadcast
        ushort4 wv4 = *(const ushort4*)wr;
        outacc[jl] = fmaf(b2f(wv4.x), tv[0], outacc[jl]);
        outacc[jl] = fmaf(b2f(wv4.y), tv[1], outacc[jl]);
        outacc[jl] = fmaf(b2f(wv4.z), tv[2], outacc[jl]);
        outacc[jl] = fmaf(b2f(wv4.w), tv[3], outacc[jl]);
      }
    }
    // next q's first __syncthreads orders these W reads before rewrites
  }

  // ---- store out[pb][c=tid][j0+jl] as FP32 (the R3-R7 bug was bf16 here) ----
  float* orow = out + ((size_t)pb * NC + tid) * NN + j0;
#pragma unroll
  for (int jl4 = 0; jl4 < 16; ++jl4) {
    f4 v;
    v[0] = outacc[jl4 * 4 + 0] * inv;
    v[1] = outacc[jl4 * 4 + 1] * inv;
    v[2] = outacc[jl4 * 4 + 2] * inv;
    v[3] = outacc[jl4 * 4 + 3] * inv;
    *(f4*)(orow + jl4 * 4) = v;
  }
}

extern "C" void kernel_launch(void* const* d_in, const int* in_sizes, int n_in,
                              void* d_out, int out_size, void* d_ws, size_t ws_size,
                              hipStream_t stream) {
  const void* temp = nullptr; const void* We = nullptr;
  const void* Wg = nullptr;   const void* pn = nullptr;
  for (int i = 0; i < n_in; ++i) {
    switch (in_sizes[i]) {
      case 4194304: temp = d_in[i]; break;
      case 65536:   We   = d_in[i]; break;
      case 256:     Wg   = d_in[i]; break;
      case 1:       pn   = d_in[i]; break;
      default: break;
    }
  }
  if (!temp) temp = d_in[0];
  if (!We)   We   = d_in[1];
  if (!Wg)   Wg   = d_in[2];
  if (!pn)   pn   = d_in[3];

  (void)d_ws; (void)ws_size;

  hipLaunchKernelGGL(k_fused, dim3(256), dim3(256), 132096, stream,
                     temp, We, Wg, pn, (float*)d_out);
}

// Round 9
// 585.611 us; speedup vs baseline: 4.2008x; 4.2008x over previous
//
#include <hip/hip_runtime.h>
#include <hip/hip_bf16.h>
#include <stdint.h>

// GraphInterConnection P=16,B=4,C=256,N=256.  R9: MFMA pipeline (validated R3
// machinery) + fp32 atomic epilogue (R8's dtype fix) + q-split occupancy.
//   corr[j,d]=sum_c tf_p[c,j]We[d,c]; A[j,i]=sum_d corr[j,d]tf_q[d,i]
//   S=softmax_i(A[j,:]); g_q[i]=sum_c Wg[c]tf_q[c,i]
//   mask[j]=sigmoid(sum_i S[j,i]g_q[i]);  W=mask*S
//   out[p,b,c,j]=(1/pn)*sum_q sum_i W[j,i]tf_q[c,i]   (fp32 output!)
// Precision: M1 3-chain split (corr hi/lo x tfT hi/lo), M2 1-chain (tf hi x W
// bf16 — W-bf16 proven at absmax 0.0039 in R8).

#define NP 16
#define NB 4
#define NC 256
#define NN 256
#define SLAB 65536

typedef __attribute__((ext_vector_type(8))) short bf16x8;
typedef __attribute__((ext_vector_type(4))) float f32x4;
typedef __attribute__((ext_vector_type(4))) float f4;

static __device__ __forceinline__ float b2f(unsigned short u) {
  union { unsigned u; float f; } x; x.u = ((unsigned)u) << 16; return x.f;
}
static __device__ __forceinline__ unsigned short f2b(float f) {
  unsigned u = __float_as_uint(f);
  u += 0x7fffu + ((u >> 16) & 1u);
  return (unsigned short)(u >> 16);
}
static __device__ __forceinline__ int is_bf16(const void* p) {
  const unsigned short* s = (const unsigned short*)p;
  int sane = 0;
  for (int i = 0; i < 64; ++i) {
    float av = fabsf(b2f(s[i]));
    sane += ((av == 0.0f) || (av > 8e-13f && av < 256.0f)) ? 1 : 0;
  }
  return sane >= 56;
}
static __device__ __forceinline__ float ld1(const void* p, size_t idx, int isb) {
  return isb ? b2f(((const unsigned short*)p)[idx]) : ((const float*)p)[idx];
}
static __device__ __forceinline__ f4 ld4(const void* p, size_t idx, int isb) {
  if (isb) {
    ushort4 v = *(const ushort4*)((const unsigned short*)p + idx);
    f4 r; r[0] = b2f(v.x); r[1] = b2f(v.y); r[2] = b2f(v.z); r[3] = b2f(v.w);
    return r;
  }
  return *(const f4*)((const float*)p + idx);
}
static __device__ __forceinline__ float read_pn(const void* p) {
  int iv = *(const int*)p;
  if (iv >= 1 && iv <= 65536) return (float)iv;
  float fv = *(const float*)p;
  if (fv >= 1.0f && fv <= 65536.0f) return fv;
  return 16.0f;
}

// ---- k_conv: temp -> th (bf16 hi only); We -> weh/wel (hi/lo); Wg -> fp32 --
__global__ __launch_bounds__(256, 1)
void k_conv(const void* tv, const void* wev, const void* wgv,
            unsigned short* __restrict__ th,
            unsigned short* __restrict__ weh, unsigned short* __restrict__ wel,
            float* __restrict__ wgf)
{
  const int bx = blockIdx.x, tid = threadIdx.x;
  if (bx < 2048) {
    const int tb = is_bf16(tv);
    const size_t base = (size_t)bx * 2048 + tid * 8;
    bf16x8 h;
#pragma unroll
    for (int s = 0; s < 2; ++s) {
      f4 v = ld4(tv, base + s * 4, tb);
#pragma unroll
      for (int k = 0; k < 4; ++k) h[s * 4 + k] = (short)f2b(v[k]);
    }
    *(bf16x8*)(th + base) = h;
  } else if (bx < 2080) {
    const int eb = is_bf16(wev);
    const size_t base = (size_t)(bx - 2048) * 2048 + tid * 8;
    bf16x8 h, l;
#pragma unroll
    for (int s = 0; s < 2; ++s) {
      f4 v = ld4(wev, base + s * 4, eb);
#pragma unroll
      for (int k = 0; k < 4; ++k) {
        unsigned short hi = f2b(v[k]);
        h[s * 4 + k] = (short)hi;
        l[s * 4 + k] = (short)f2b(v[k] - b2f(hi));
      }
    }
    *(bf16x8*)(weh + base) = h;
    *(bf16x8*)(wel + base) = l;
  } else {
    if (tid < 64) {
      const int gb = is_bf16(wgv);
      f4 v = ld4(wgv, tid * 4, gb);
      *(f4*)(wgf + tid * 4) = v;
    }
  }
}

// ---- k_prep: transpose + tfT hi/lo + g + corr hi/lo (MFMA 3-chain) -------
// grid 512 = pb(64) x cb(8 chunks of 32 spatial rows)
__global__ __launch_bounds__(256, 1)
void k_prep(const void* __restrict__ tempv,
            const unsigned short* __restrict__ weh, const unsigned short* __restrict__ wel,
            const float* __restrict__ wgf,
            unsigned short* __restrict__ tfTh, unsigned short* __restrict__ tfTl,
            unsigned short* __restrict__ corrh, unsigned short* __restrict__ corrl,
            float* __restrict__ gws)
{
  __shared__ float smT[32 * 264];   // [row=i-local][c] fp32
  __shared__ float gpart[256];
  const int bx = blockIdx.x;
  const int pb = bx >> 3, cb = bx & 7;
  const int tid = threadIdx.x;
  const int lane = tid & 63, wave = tid >> 6;
  const int l15 = lane & 15, quad = lane >> 4;
  const int tb = is_bf16(tempv);

  // stage: temp[pb][c=tid][cb*32 + k] -> smT[k][c]
#pragma unroll
  for (int s = 0; s < 8; ++s) {
    f4 v = ld4(tempv, (size_t)pb * SLAB + (size_t)tid * NN + cb * 32 + s * 4, tb);
#pragma unroll
    for (int w = 0; w < 4; ++w) smT[(s * 4 + w) * 264 + tid] = v[w];
  }
  __syncthreads();

  // tfT hi/lo (coalesced) + g partials
  {
#pragma unroll
    for (int s = 0; s < 4; ++s) {
      int f = s * 256 + tid;
      int row = f >> 5, kb = f & 31;
      bf16x8 vh, vl;
#pragma unroll
      for (int e = 0; e < 8; ++e) {
        float v = smT[row * 264 + kb * 8 + e];
        unsigned short hi = f2b(v);
        vh[e] = (short)hi;
        vl[e] = (short)f2b(v - b2f(hi));
      }
      size_t o = (size_t)pb * SLAB + (size_t)(cb * 32 + row) * NN + kb * 8;
      *(bf16x8*)(tfTh + o) = vh;
      *(bf16x8*)(tfTl + o) = vl;
    }
    const int row = tid >> 3, grp = tid & 7;
    float a = 0.f;
#pragma unroll
    for (int u = 0; u < 32; ++u) {
      int c = grp * 32 + u;
      a = fmaf(smT[row * 264 + c], wgf[c], a);
    }
    gpart[tid] = a;
  }
  __syncthreads();
  if (tid < 32) {
    float g = 0.f;
#pragma unroll
    for (int k = 0; k < 8; ++k) g += gpart[tid * 8 + k];
    gws[pb * NN + cb * 32 + tid] = g;
  }

  // corr[j,d] = sum_c tf[c,j]We[d,c] (3-chain). wave -> (jt, dhalf)
  {
    const int jt = wave & 1, dh = wave >> 1;
    bf16x8 ah[8], al[8];
#pragma unroll
    for (int kk = 0; kk < 8; ++kk) {
#pragma unroll
      for (int e = 0; e < 8; ++e) {
        float v = smT[(jt * 16 + l15) * 264 + kk * 32 + quad * 8 + e];
        unsigned short hi = f2b(v);
        ah[kk][e] = (short)hi;
        al[kk][e] = (short)f2b(v - b2f(hi));
      }
    }
    for (int dt = 0; dt < 8; ++dt) {
      const int dbase = dh * 128 + dt * 16;
      f32x4 acc = {0.f, 0.f, 0.f, 0.f};
#pragma unroll
      for (int kk = 0; kk < 8; ++kk) {
        bf16x8 bh = *(const bf16x8*)(weh + (size_t)(dbase + l15) * NC + kk * 32 + quad * 8);
        bf16x8 bl = *(const bf16x8*)(wel + (size_t)(dbase + l15) * NC + kk * 32 + quad * 8);
        acc = __builtin_amdgcn_mfma_f32_16x16x32_bf16(al[kk], bh, acc, 0, 0, 0);
        acc = __builtin_amdgcn_mfma_f32_16x16x32_bf16(ah[kk], bl, acc, 0, 0, 0);
        acc = __builtin_amdgcn_mfma_f32_16x16x32_bf16(ah[kk], bh, acc, 0, 0, 0);
      }
#pragma unroll
      for (int r = 0; r < 4; ++r) {
        int j = cb * 32 + jt * 16 + quad * 4 + r;
        int d = dbase + l15;
        unsigned short hi = f2b(acc[r]);
        float lo = acc[r] - b2f(hi);
        size_t off = (size_t)pb * SLAB + (size_t)j * NC + d;
        corrh[off] = hi;
        corrl[off] = f2b(lo);
      }
    }
  }
}

// ---- k_main: MFMA attention, q-split, atomic fp32 epilogue ---------------
// grid 512 = pb(64) x jt(4) x qh(2); 256 threads (wave -> 16 j rows)
// LDS: stg 32KB (M1: hi|lo 32-row halves; M2: 64 c-rows) + Wball 16KB + gq 1KB
__global__ __launch_bounds__(256, 2)
void k_main(const unsigned short* __restrict__ th,
            const unsigned short* __restrict__ tfTh, const unsigned short* __restrict__ tfTl,
            const unsigned short* __restrict__ corrh, const unsigned short* __restrict__ corrl,
            const float* __restrict__ gws, const void* __restrict__ pnv,
            float* __restrict__ out)
{
  __shared__ unsigned short stg[64 * 256];
  __shared__ unsigned short Wball[4 * 16 * 256];
  __shared__ float gq[256];
  const int bx = blockIdx.x;
  const int pb = bx >> 3;
  const int b  = pb & 3;
  const int jt = (bx >> 1) & 3;
  const int qh = bx & 1;
  const int tid = threadIdx.x;
  const int lane = tid & 63, wave = tid >> 6;
  const int l15 = lane & 15, quad = lane >> 4;
  const int jbaseW = jt * 64 + wave * 16;
  unsigned short* Wb = Wball + wave * 4096;
  unsigned short* sgh = stg;
  unsigned short* sgl = stg + 32 * 256;

  // resident corr A-frags (hi/lo), reused across all 8 q of this half
  bf16x8 chf[8], clf[8];
#pragma unroll
  for (int kk = 0; kk < 8; ++kk) {
    size_t off = (size_t)pb * SLAB + (size_t)(jbaseW + l15) * NC + kk * 32 + quad * 8;
    chf[kk] = *(const bf16x8*)(corrh + off);
    clf[kk] = *(const bf16x8*)(corrl + off);
  }

  const f32x4 fz = {0.f, 0.f, 0.f, 0.f};
  f32x4 outacc[16];
#pragma unroll
  for (int t = 0; t < 16; ++t) outacc[t] = fz;
  const float inv = 1.0f / read_pn(pnv);

  for (int qi = 0; qi < 8; ++qi) {
    const int q = qh * 8 + qi;
    const size_t slab = (size_t)(q * NB + b) * SLAB;

    f32x4 Aacc[16];
#pragma unroll
    for (int t = 0; t < 16; ++t) Aacc[t] = fz;

    // ---- M1: A[16j x 256i], 8 chunks of 32 i-rows, 3-chain split ----
    for (int ch = 0; ch < 8; ++ch) {
      __syncthreads();
      {
        const unsigned short* sh = tfTh + slab + (size_t)ch * 32 * NN;
        const unsigned short* sl = tfTl + slab + (size_t)ch * 32 * NN;
#pragma unroll
        for (int s = 0; s < 4; ++s) {
          int f = s * 256 + tid;
          int row = f >> 5, kb = f & 31;
          int dst = row * 256 + ((kb ^ (row & 15)) * 8);
          *(bf16x8*)(sgh + dst) = *(const bf16x8*)(sh + f * 8);
          *(bf16x8*)(sgl + dst) = *(const bf16x8*)(sl + f * 8);
        }
        if (ch == 0) gq[tid] = gws[(q * NB + b) * NN + tid];
      }
      __syncthreads();
#pragma unroll
      for (int it = 0; it < 2; ++it) {
        const int tg = ch * 2 + it;
#pragma unroll
        for (int kk = 0; kk < 8; ++kk) {
          int src = (it * 16 + l15) * 256 + (((kk * 4 + quad) ^ l15) * 8);
          bf16x8 bh = *(const bf16x8*)(sgh + src);
          bf16x8 bl = *(const bf16x8*)(sgl + src);
          Aacc[tg] = __builtin_amdgcn_mfma_f32_16x16x32_bf16(clf[kk], bh, Aacc[tg], 0, 0, 0);
          Aacc[tg] = __builtin_amdgcn_mfma_f32_16x16x32_bf16(chf[kk], bl, Aacc[tg], 0, 0, 0);
          Aacc[tg] = __builtin_amdgcn_mfma_f32_16x16x32_bf16(chf[kk], bh, Aacc[tg], 0, 0, 0);
        }
      }
    }

    // ---- softmax over i + fused gate; W = mask*S -> Wb (bf16, swizzled) --
#pragma unroll
    for (int r = 0; r < 4; ++r) {
      float m = -1e30f;
#pragma unroll
      for (int t = 0; t < 16; ++t) m = fmaxf(m, Aacc[t][r]);
      m = fmaxf(m, __shfl_xor(m, 1)); m = fmaxf(m, __shfl_xor(m, 2));
      m = fmaxf(m, __shfl_xor(m, 4)); m = fmaxf(m, __shfl_xor(m, 8));
      float z = 0.f, s = 0.f;
#pragma unroll
      for (int t = 0; t < 16; ++t) {
        float e = __expf(Aacc[t][r] - m);
        Aacc[t][r] = e;
        z += e;
        s = fmaf(e, gq[t * 16 + l15], s);
      }
      z += __shfl_xor(z, 1); z += __shfl_xor(z, 2); z += __shfl_xor(z, 4); z += __shfl_xor(z, 8);
      s += __shfl_xor(s, 1); s += __shfl_xor(s, 2); s += __shfl_xor(s, 4); s += __shfl_xor(s, 8);
      float rz = 1.f / z;
      float mask = 1.f / (1.f + __expf(-s * rz));
      float sc = mask * rz;
      const int jr = quad * 4 + r;
#pragma unroll
      for (int t = 0; t < 16; ++t) {
        int col = t * 16 + l15;
        int cbk = col >> 3, e = col & 7;
        Wb[jr * 256 + ((cbk ^ jr) * 8) + e] = f2b(Aacc[t][r] * sc);
      }
    }

    // B-frags of W (same wave wrote its private Wb; same-wave DS ordered)
    bf16x8 wf[8];
#pragma unroll
    for (int kk = 0; kk < 8; ++kk) {
      int kb = kk * 4 + quad;
      wf[kk] = *(const bf16x8*)(Wb + l15 * 256 + ((kb ^ l15) * 8));
    }

    // ---- M2: outacc[256c x 16j] += tf_q @ W^T, 4 chunks of 64 c-rows ----
    for (int ch = 0; ch < 4; ++ch) {
      __syncthreads();
      {
        const unsigned short* sh = th + slab + (size_t)ch * 64 * NN;
#pragma unroll
        for (int s = 0; s < 8; ++s) {
          int f = s * 256 + tid;
          int row = f >> 5, kb = f & 31;
          int dst = row * 256 + ((kb ^ (row & 15)) * 8);
          *(bf16x8*)(stg + dst) = *(const bf16x8*)(sh + f * 8);
        }
      }
      __syncthreads();
#pragma unroll
      for (int ct = 0; ct < 4; ++ct) {
        const int tg = ch * 4 + ct;
#pragma unroll
        for (int kk = 0; kk < 8; ++kk) {
          int src = (ct * 16 + l15) * 256 + (((kk * 4 + quad) ^ l15) * 8);
          bf16x8 afr = *(const bf16x8*)(stg + src);
          outacc[tg] = __builtin_amdgcn_mfma_f32_16x16x32_bf16(afr, wf[kk], outacc[tg], 0, 0, 0);
        }
      }
    }
  }

  // ---- epilogue: fp32 atomic accumulate (two qh blocks per output) ----
#pragma unroll
  for (int t = 0; t < 16; ++t) {
#pragma unroll
    for (int r = 0; r < 4; ++r) {
      int c = t * 16 + quad * 4 + r;
      int j = jbaseW + l15;
      atomicAdd(out + ((size_t)pb * NC + c) * NN + j, outacc[t][r] * inv);
    }
  }
}

extern "C" void kernel_launch(void* const* d_in, const int* in_sizes, int n_in,
                              void* d_out, int out_size, void* d_ws, size_t ws_size,
                              hipStream_t stream) {
  const void* temp = nullptr; const void* We = nullptr;
  const void* Wg = nullptr;   const void* pn = nullptr;
  for (int i = 0; i < n_in; ++i) {
    switch (in_sizes[i]) {
      case 4194304: temp = d_in[i]; break;
      case 65536:   We   = d_in[i]; break;
      case 256:     Wg   = d_in[i]; break;
      case 1:       pn   = d_in[i]; break;
      default: break;
    }
  }
  if (!temp) temp = d_in[0];
  if (!We)   We   = d_in[1];
  if (!Wg)   Wg   = d_in[2];
  if (!pn)   pn   = d_in[3];

  char* ws = (char*)d_ws;
  unsigned short* th    = (unsigned short*)(ws);              //  8 MB  [pb][c][i] bf16 hi
  unsigned short* tfTh  = (unsigned short*)(ws +  8388608);   //  8 MB  [pb][i][c] hi
  unsigned short* tfTl  = (unsigned short*)(ws + 16777216);   //  8 MB  [pb][i][c] lo
  unsigned short* corrh = (unsigned short*)(ws + 25165824);   //  8 MB  [pb][j][d] hi
  unsigned short* corrl = (unsigned short*)(ws + 33554432);   //  8 MB  [pb][j][d] lo
  unsigned short* weh   = (unsigned short*)(ws + 41943040);   // 128 KB
  unsigned short* wel   = (unsigned short*)(ws + 42074112);   // 128 KB
  float*          gws   = (float*)         (ws + 42205184);   //  64 KB
  float*          wgf   = (float*)         (ws + 42270720);   //   1 KB

  hipMemsetAsync(d_out, 0, (size_t)out_size * sizeof(float), stream);
  hipLaunchKernelGGL(k_conv, dim3(2081), dim3(256), 0, stream,
                     temp, We, Wg, th, weh, wel, wgf);
  hipLaunchKernelGGL(k_prep, dim3(512), dim3(256), 0, stream,
                     temp, weh, wel, wgf, tfTh, tfTl, corrh, corrl, gws);
  hipLaunchKernelGGL(k_main, dim3(512), dim3(256), 0, stream,
                     th, tfTh, tfTl, corrh, corrl, gws, pn, (float*)d_out);
}